// Round 1
// baseline (165.138 us; speedup 1.0000x reference)
//
#include <hip/hip_runtime.h>
#include <hip/hip_bf16.h>

typedef __bf16 bf16;
typedef __attribute__((ext_vector_type(2))) __bf16 bf16x2;
typedef __attribute__((ext_vector_type(4))) __bf16 bf16x4;
typedef __attribute__((ext_vector_type(8))) __bf16 bf16x8;
typedef __attribute__((ext_vector_type(4))) float f32x4;

#define NB 4
#define NS 1024
#define NE 1024
#define NH 16
#define ND 64
#define NROT 32
#define NM (NB*NS)   // 4096 rows

// ---- async global->LDS, 16B per lane, wave-uniform LDS base ----
__device__ __forceinline__ void gload_lds16(const bf16* g, void* l) {
  __builtin_amdgcn_global_load_lds(
      (const __attribute__((address_space(1))) unsigned int*)g,
      (__attribute__((address_space(3))) unsigned int*)l,
      16, 0, 0);
}

// ---- f32 -> bf16 convert, vectorized ----
__global__ void k_cvt(const float* __restrict__ src, bf16* __restrict__ dst, int n4) {
  int i = blockIdx.x * 256 + threadIdx.x;
  if (i >= n4) return;
  float4 v = reinterpret_cast<const float4*>(src)[i];
  bf16x4 o = { (bf16)v.x, (bf16)v.y, (bf16)v.z, (bf16)v.w };
  *reinterpret_cast<bf16x4*>(dst + (size_t)i * 4) = o;
}

// ---- rope cos/sin tables ----
__global__ void k_tab(const float* __restrict__ rot, float* __restrict__ ct,
                      float* __restrict__ st, int n) {
  int i = blockIdx.x * 256 + threadIdx.x;
  if (i >= n) return;
  float v = rot[i];
  ct[i] = cosf(v);
  st[i] = sinf(v);
}

// ---- GEMM: out = A(4096x1024) * W(1024x1024)^T ----
// EPI=0: qkv epilogue (scale + rope, bf16 out). EPI=1: bias epilogue (f32 out).
template<int EPI>
__global__ __launch_bounds__(256) void k_gemm(
    const bf16* __restrict__ A, const bf16* __restrict__ W, void* __restrict__ outp,
    float scale, const float* __restrict__ ct, const float* __restrict__ st,
    const float* __restrict__ bias)
{
  __shared__ bf16 lA[128 * 64];
  __shared__ bf16 lB[128 * 64];
  const int tid = threadIdx.x;
  const int wave = tid >> 6, lane = tid & 63;
  const int wm = wave >> 1, wn = wave & 1;       // 2x2 wave grid, 64x64 each
  const int fr = lane & 15, kg = lane >> 4;
  const int m0 = blockIdx.x * 128, n0 = blockIdx.y * 128;

  f32x4 acc[4][4] = {};

  const int lrow8 = lane >> 3;   // 0..7 (which 16B-octet row within 1KB chunk)
  const int lslot = lane & 7;    // 16B slot within 128B row

  for (int kt = 0; kt < NE; kt += 64) {
    // stage A and B tiles (128x64 bf16 each = 16KB), XOR-swizzled source
    for (int i = 0; i < 4; ++i) {
      int chunk = i * 4 + wave;                  // 0..15
      int bbase = chunk * 1024;                  // byte base in LDS
      int row = (chunk << 3) + lrow8;            // 0..127
      int slot = lslot ^ (row & 7);              // logical 16B slot
      gload_lds16(A + (size_t)(m0 + row) * NE + kt + slot * 8, (char*)lA + bbase);
      gload_lds16(W + (size_t)(n0 + row) * NE + kt + slot * 8, (char*)lB + bbase);
    }
    __syncthreads();
    for (int kk = 0; kk < 2; ++kk) {
      bf16x8 af[4], bfr[4];
      for (int i = 0; i < 4; ++i) {
        int ra = wm * 64 + i * 16 + fr;
        af[i] = *reinterpret_cast<const bf16x8*>(lA + ra * 64 + (((kg + 4 * kk) ^ (ra & 7)) << 3));
        int rb = wn * 64 + i * 16 + fr;
        bfr[i] = *reinterpret_cast<const bf16x8*>(lB + rb * 64 + (((kg + 4 * kk) ^ (rb & 7)) << 3));
      }
      for (int i = 0; i < 4; ++i)
        for (int j = 0; j < 4; ++j)
          acc[i][j] = __builtin_amdgcn_mfma_f32_16x16x32_bf16(af[i], bfr[j], acc[i][j], 0, 0, 0);
    }
    __syncthreads();
  }

  // epilogue. D layout: row = kg*4+r, col = fr (within each 16x16 frag)
  if (EPI == 0) {
    bf16* o = (bf16*)outp;
    for (int i = 0; i < 4; ++i) {
      int rowbase = m0 + wm * 64 + i * 16 + kg * 4;
      for (int r = 0; r < 4; ++r) {
        int gm = rowbase + r;
        int s = gm & (NS - 1);
        // wave covers exactly one head (64 aligned cols): frag j=0 -> d=fr, j=1 -> d=16+fr
        float x0 = acc[i][0][r] * scale;
        float x1 = acc[i][1][r] * scale;
        float c0 = ct[s * NROT + fr],      sn0 = st[s * NROT + fr];
        float c1 = ct[s * NROT + 16 + fr], sn1 = st[s * NROT + 16 + fr];
        float y0 = x0 * c0 - x1 * sn0;
        float y1 = x1 * c1 + x0 * sn1;
        size_t rb = (size_t)gm * NE + n0 + wn * 64;
        o[rb + 0 * 16 + fr] = (bf16)y0;
        o[rb + 1 * 16 + fr] = (bf16)y1;
        o[rb + 2 * 16 + fr] = (bf16)(acc[i][2][r] * scale);
        o[rb + 3 * 16 + fr] = (bf16)(acc[i][3][r] * scale);
      }
    }
  } else {
    float* o = (float*)outp;
    for (int i = 0; i < 4; ++i)
      for (int j = 0; j < 4; ++j) {
        int gc = n0 + wn * 64 + j * 16 + fr;
        float bv = bias[gc];
        for (int r = 0; r < 4; ++r) {
          int gm = m0 + wm * 64 + i * 16 + kg * 4 + r;
          o[(size_t)gm * NE + gc] = acc[i][j][r] + bv;
        }
      }
  }
}

// fused QKV wrapper: blockIdx.z selects q/k/v
__global__ __launch_bounds__(256) void k_gemm_qkv(
    const bf16* __restrict__ A,
    const bf16* __restrict__ Wq, const bf16* __restrict__ Wk, const bf16* __restrict__ Wv,
    bf16* __restrict__ Oq, bf16* __restrict__ Ok, bf16* __restrict__ Ov,
    const float* __restrict__ ct, const float* __restrict__ st);

// Implemented by re-dispatch trick is messy; instead duplicate the body via a device function.
// Simpler: just declare three separate launches of k_gemm<0> from host (see kernel_launch).

// ---- flash attention: causal, per (q-tile, b*h) block ----
// Q,K,V,O all [NM][NE] bf16 row-major; head h occupies cols h*64..h*64+63.
__global__ __launch_bounds__(256) void k_attn(
    const bf16* __restrict__ Q, const bf16* __restrict__ K,
    const bf16* __restrict__ V, bf16* __restrict__ O)
{
  __shared__ bf16 lK[64 * 64];
  __shared__ bf16 lVT[64 * 64];
  __shared__ bf16 lP[4][16 * 72];   // per-wave P tile, padded stride 72
  const int tid = threadIdx.x;
  const int wave = tid >> 6, lane = tid & 63;
  const int fr = lane & 15, kg = lane >> 4;
  const int qt = blockIdx.x;                     // q tile (64 rows)
  const int bh = blockIdx.y;
  const int b = bh >> 4, h = bh & 15;
  const int q0 = qt * 64;
  const size_t hbase = (size_t)b * NS * NE + h * 64;
  const bf16* Qb = Q + hbase;
  const bf16* Kb = K + hbase;
  const bf16* Vb = V + hbase;

  // hoist Q fragments (A-operand: supply row = fr, k = kg*8 + kk*32 + j)
  bf16x8 qf[2];
  for (int kk = 0; kk < 2; ++kk)
    qf[kk] = *reinterpret_cast<const bf16x8*>(
        Qb + (size_t)(q0 + wave * 16 + fr) * NE + kk * 32 + kg * 8);

  f32x4 oacc[4] = {};
  float mrow[4], lsum[4];
  for (int r = 0; r < 4; ++r) { mrow[r] = -3.0e38f; lsum[r] = 0.f; }

  const int vkv = (tid & 31) * 2;      // even kv row this thread transposes
  const int vd0 = (tid >> 5) * 8;      // 8 d-columns

  for (int t = 0; t <= qt; ++t) {
    const int kv0 = t * 64;
    __syncthreads();   // previous tile fully consumed
    // stage K tile [64][64], swizzled (slot ^= row&7), via global_load_lds
    for (int i = 0; i < 2; ++i) {
      int chunk = i * 4 + wave;                  // 0..7
      int row = (chunk << 3) + (lane >> 3);      // 0..63
      int slot = (lane & 7) ^ (row & 7);
      gload_lds16(Kb + (size_t)(kv0 + row) * NE + slot * 8, (char*)lK + chunk * 1024);
    }
    // stage V transposed: lVT[d][kv], swizzled 16B slots along kv
    {
      bf16x8 v0 = *reinterpret_cast<const bf16x8*>(Vb + (size_t)(kv0 + vkv) * NE + vd0);
      bf16x8 v1 = *reinterpret_cast<const bf16x8*>(Vb + (size_t)(kv0 + vkv + 1) * NE + vd0);
      for (int e = 0; e < 8; ++e) {
        int d = vd0 + e;
        int byteoff = d * 128 + ((((vkv >> 3) ^ (d & 7))) << 4) + (vkv & 7) * 2;
        bf16x2 pr = { v0[e], v1[e] };
        *reinterpret_cast<bf16x2*>((char*)lVT + byteoff) = pr;
      }
    }
    __syncthreads();

    // QK^T: S[q=kg*4+r][kv=j*16+fr]
    f32x4 sacc[4] = {};
    for (int kk = 0; kk < 2; ++kk)
      for (int j = 0; j < 4; ++j) {
        int rc = j * 16 + fr;
        bf16x8 kf = *reinterpret_cast<const bf16x8*>(
            lK + rc * 64 + (((kg + 4 * kk) ^ (rc & 7)) << 3));
        sacc[j] = __builtin_amdgcn_mfma_f32_16x16x32_bf16(qf[kk], kf, sacc[j], 0, 0, 0);
      }

    if (t == qt) {   // causal mask on the diagonal tile
      for (int j = 0; j < 4; ++j)
        for (int r = 0; r < 4; ++r)
          if (j * 16 + fr > wave * 16 + kg * 4 + r) sacc[j][r] = -3.0e38f;
    }

    // online softmax per owned row (16 lanes share a row; kg*4+r indexes it)
    for (int r = 0; r < 4; ++r) {
      float tm = fmaxf(fmaxf(sacc[0][r], sacc[1][r]), fmaxf(sacc[2][r], sacc[3][r]));
      for (int msk = 1; msk < 16; msk <<= 1) tm = fmaxf(tm, __shfl_xor(tm, msk));
      float nm = fmaxf(mrow[r], tm);
      float corr = __expf(mrow[r] - nm);
      float ps = 0.f;
      for (int j = 0; j < 4; ++j) {
        float p = __expf(sacc[j][r] - nm);
        ps += p;
        lP[wave][(kg * 4 + r) * 72 + j * 16 + fr] = (bf16)p;
      }
      for (int msk = 1; msk < 16; msk <<= 1) ps += __shfl_xor(ps, msk);
      lsum[r] = lsum[r] * corr + ps;
      mrow[r] = nm;
      for (int df = 0; df < 4; ++df) oacc[df][r] *= corr;
    }

    // PV: A = P (row supply = fr, k = kv), B = V^T tile
    for (int ks = 0; ks < 2; ++ks) {
      bf16x8 pf = *reinterpret_cast<const bf16x8*>(&lP[wave][fr * 72 + ks * 32 + kg * 8]);
      for (int df = 0; df < 4; ++df) {
        int d = df * 16 + fr;
        bf16x8 vf = *reinterpret_cast<const bf16x8*>(
            (char*)lVT + d * 128 + (((kg + 4 * ks) ^ (d & 7)) << 4));
        oacc[df] = __builtin_amdgcn_mfma_f32_16x16x32_bf16(pf, vf, oacc[df], 0, 0, 0);
      }
    }
  }

  // epilogue: O[b*NS + q0 + wave*16 + kg*4 + r][h*64 + df*16 + fr]
  for (int df = 0; df < 4; ++df)
    for (int r = 0; r < 4; ++r) {
      size_t gm = (size_t)b * NS + q0 + wave * 16 + kg * 4 + r;
      O[gm * NE + h * 64 + df * 16 + fr] = (bf16)(oacc[df][r] / lsum[r]);
    }
}

extern "C" void kernel_launch(void* const* d_in, const int* in_sizes, int n_in,
                              void* d_out, int out_size, void* d_ws, size_t ws_size,
                              hipStream_t stream) {
  const float* hs  = (const float*)d_in[0];
  const float* rot = (const float*)d_in[1];
  const float* qw  = (const float*)d_in[2];
  const float* kw  = (const float*)d_in[3];
  const float* vw  = (const float*)d_in[4];
  const float* ow  = (const float*)d_in[5];
  const float* obb = (const float*)d_in[6];
  float* out = (float*)d_out;

  char* ws = (char*)d_ws;
  size_t off = 0;
  bf16* hb  = (bf16*)(ws + off); off += (size_t)NM * NE * 2;
  bf16* wqb = (bf16*)(ws + off); off += (size_t)NE * NE * 2;
  bf16* wkb = (bf16*)(ws + off); off += (size_t)NE * NE * 2;
  bf16* wvb = (bf16*)(ws + off); off += (size_t)NE * NE * 2;
  bf16* wob = (bf16*)(ws + off); off += (size_t)NE * NE * 2;
  bf16* qb  = (bf16*)(ws + off); off += (size_t)NM * NE * 2;
  bf16* kb  = (bf16*)(ws + off); off += (size_t)NM * NE * 2;
  bf16* vb  = (bf16*)(ws + off); off += (size_t)NM * NE * 2;
  float* ct = (float*)(ws + off); off += (size_t)NS * NROT * 4;
  float* st = (float*)(ws + off); off += (size_t)NS * NROT * 4;
  bf16* aob = hb;   // reuse: hidden bf16 is dead after QKV GEMMs

  // prep
  k_cvt<<<dim3((NM * NE / 4 + 255) / 256), dim3(256), 0, stream>>>(hs, hb, NM * NE / 4);
  k_cvt<<<dim3((NE * NE / 4 + 255) / 256), dim3(256), 0, stream>>>(qw, wqb, NE * NE / 4);
  k_cvt<<<dim3((NE * NE / 4 + 255) / 256), dim3(256), 0, stream>>>(kw, wkb, NE * NE / 4);
  k_cvt<<<dim3((NE * NE / 4 + 255) / 256), dim3(256), 0, stream>>>(vw, wvb, NE * NE / 4);
  k_cvt<<<dim3((NE * NE / 4 + 255) / 256), dim3(256), 0, stream>>>(ow, wob, NE * NE / 4);
  k_tab<<<dim3((NS * NROT + 255) / 256), dim3(256), 0, stream>>>(rot, ct, st, NS * NROT);

  // QKV projections + rope (scale only on q)
  dim3 gg(NM / 128, NE / 128);
  const float scale = 0.125f;  // D^-0.5
  k_gemm<0><<<gg, dim3(256), 0, stream>>>(hb, wqb, qb, scale, ct, st, nullptr);
  k_gemm<0><<<gg, dim3(256), 0, stream>>>(hb, wkb, kb, 1.0f, ct, st, nullptr);
  k_gemm<0><<<gg, dim3(256), 0, stream>>>(hb, wvb, vb, 1.0f, ct, st, nullptr);

  // causal flash attention
  k_attn<<<dim3(NS / 64, NB * NH), dim3(256), 0, stream>>>(qb, kb, vb, aob);

  // output projection + bias
  k_gemm<1><<<gg, dim3(256), 0, stream>>>(aob, wob, out, 1.0f, nullptr, nullptr, obb);

  (void)in_sizes; (void)n_in; (void)out_size; (void)ws_size;
}

// Round 2
// 140.317 us; speedup vs baseline: 1.1769x; 1.1769x over previous
//
#include <hip/hip_runtime.h>
#include <hip/hip_bf16.h>

typedef __bf16 bf16;
typedef __attribute__((ext_vector_type(2))) __bf16 bf16x2;
typedef __attribute__((ext_vector_type(4))) __bf16 bf16x4;
typedef __attribute__((ext_vector_type(8))) __bf16 bf16x8;
typedef __attribute__((ext_vector_type(4))) float f32x4;

#define NB 4
#define NS 1024
#define NE 1024
#define NH 16
#define ND 64
#define NROT 32
#define NM (NB*NS)   // 4096 rows

// ---- async global->LDS, 16B per lane, wave-uniform LDS base ----
__device__ __forceinline__ void gload_lds16(const bf16* g, void* l) {
  __builtin_amdgcn_global_load_lds(
      (const __attribute__((address_space(1))) unsigned int*)g,
      (__attribute__((address_space(3))) unsigned int*)l,
      16, 0, 0);
}

// ---- DPP 16-lane rotate-reduce helpers (VALU pipe, not LDS) ----
template<int CTRL>
__device__ __forceinline__ float fmax_dpp(float x) {
  int y = __builtin_amdgcn_update_dpp(__float_as_int(x), __float_as_int(x),
                                      CTRL, 0xF, 0xF, false);
  return fmaxf(x, __int_as_float(y));
}
template<int CTRL>
__device__ __forceinline__ float fadd_dpp(float x) {
  int y = __builtin_amdgcn_update_dpp(__float_as_int(x), __float_as_int(x),
                                      CTRL, 0xF, 0xF, false);
  return x + __int_as_float(y);
}

// ---- f32 -> bf16 convert, vectorized ----
__global__ void k_cvt(const float* __restrict__ src, bf16* __restrict__ dst, int n4) {
  int i = blockIdx.x * 256 + threadIdx.x;
  if (i >= n4) return;
  float4 v = reinterpret_cast<const float4*>(src)[i];
  bf16x4 o = { (bf16)v.x, (bf16)v.y, (bf16)v.z, (bf16)v.w };
  *reinterpret_cast<bf16x4*>(dst + (size_t)i * 4) = o;
}

struct Cvt4Args {
  const float* s0; const float* s1; const float* s2; const float* s3;
  bf16* d0; bf16* d1; bf16* d2; bf16* d3;
};
__global__ void k_cvt4(Cvt4Args a, int n4) {
  const float* s; bf16* d;
  switch (blockIdx.y) {
    case 0:  s = a.s0; d = a.d0; break;
    case 1:  s = a.s1; d = a.d1; break;
    case 2:  s = a.s2; d = a.d2; break;
    default: s = a.s3; d = a.d3; break;
  }
  int i = blockIdx.x * 256 + threadIdx.x;
  if (i >= n4) return;
  float4 v = reinterpret_cast<const float4*>(s)[i];
  bf16x4 o = { (bf16)v.x, (bf16)v.y, (bf16)v.z, (bf16)v.w };
  *reinterpret_cast<bf16x4*>(d + (size_t)i * 4) = o;
}

// ---- rope cos/sin tables ----
__global__ void k_tab(const float* __restrict__ rot, float* __restrict__ ct,
                      float* __restrict__ st, int n) {
  int i = blockIdx.x * 256 + threadIdx.x;
  if (i >= n) return;
  float v = rot[i];
  ct[i] = cosf(v);
  st[i] = sinf(v);
}

// ---- shared GEMM core: acc += A(tile BMx64) * W(tile BNx64)^T over K=NE ----
template<int BM, int BN>
__device__ __forceinline__ void gemm_core(
    const bf16* __restrict__ A, const bf16* __restrict__ W,
    bf16* lA, bf16* lB, int m0, int n0, f32x4 (&acc)[BM/32][BN/32])
{
  const int tid = threadIdx.x;
  const int wave = tid >> 6, lane = tid & 63;
  const int wm = wave >> 1, wn = wave & 1;
  const int fr = lane & 15, kg = lane >> 4;
  const int lrow8 = lane >> 3, lslot = lane & 7;

  for (int kt = 0; kt < NE; kt += 64) {
#pragma unroll
    for (int i = 0; i < BM / 32; ++i) {
      int chunk = i * 4 + wave;
      int row = (chunk << 3) + lrow8;
      int slot = lslot ^ (row & 7);
      gload_lds16(A + (size_t)(m0 + row) * NE + kt + slot * 8, (char*)lA + chunk * 1024);
    }
#pragma unroll
    for (int i = 0; i < BN / 32; ++i) {
      int chunk = i * 4 + wave;
      int row = (chunk << 3) + lrow8;
      int slot = lslot ^ (row & 7);
      gload_lds16(W + (size_t)(n0 + row) * NE + kt + slot * 8, (char*)lB + chunk * 1024);
    }
    __syncthreads();
#pragma unroll
    for (int kk = 0; kk < 2; ++kk) {
      bf16x8 af[BM / 32], bfr[BN / 32];
#pragma unroll
      for (int i = 0; i < BM / 32; ++i) {
        int ra = wm * (BM / 2) + i * 16 + fr;
        af[i] = *reinterpret_cast<const bf16x8*>(lA + ra * 64 + (((kg + 4 * kk) ^ (ra & 7)) << 3));
      }
#pragma unroll
      for (int j = 0; j < BN / 32; ++j) {
        int rb = wn * (BN / 2) + j * 16 + fr;
        bfr[j] = *reinterpret_cast<const bf16x8*>(lB + rb * 64 + (((kg + 4 * kk) ^ (rb & 7)) << 3));
      }
#pragma unroll
      for (int i = 0; i < BM / 32; ++i)
#pragma unroll
        for (int j = 0; j < BN / 32; ++j)
          acc[i][j] = __builtin_amdgcn_mfma_f32_16x16x32_bf16(af[i], bfr[j], acc[i][j], 0, 0, 0);
    }
    __syncthreads();
  }
}

// ---- fused QKV projection + rope: z selects q/k/v ----
__global__ __launch_bounds__(256) void k_gemm_qkv(
    const bf16* __restrict__ A, const bf16* __restrict__ Wq, const bf16* __restrict__ Wk,
    const bf16* __restrict__ Wv, bf16* __restrict__ Oq, bf16* __restrict__ Ok,
    bf16* __restrict__ Ov, const float* __restrict__ ct, const float* __restrict__ st)
{
  __shared__ bf16 lA[128 * 64];
  __shared__ bf16 lB[128 * 64];
  const int z = blockIdx.z;
  const bf16* W = (z == 0) ? Wq : (z == 1) ? Wk : Wv;
  bf16* Og = (z == 0) ? Oq : (z == 1) ? Ok : Ov;
  // q carries D^-0.5 * log2(e) so softmax can run in exp2 domain
  const float scale = (z == 0) ? 0.125f * 1.44269504f : 1.0f;
  const int m0 = blockIdx.x * 128, n0 = blockIdx.y * 128;

  f32x4 acc[4][4] = {};
  gemm_core<128, 128>(A, W, lA, lB, m0, n0, acc);

  const int tid = threadIdx.x;
  const int wave = tid >> 6, lane = tid & 63;
  const int wm = wave >> 1, wn = wave & 1;
  const int fr = lane & 15, kg = lane >> 4;

#pragma unroll
  for (int i = 0; i < 4; ++i) {
    int rowbase = m0 + wm * 64 + i * 16 + kg * 4;
#pragma unroll
    for (int r = 0; r < 4; ++r) {
      int gm = rowbase + r;
      int s = gm & (NS - 1);
      float x0 = acc[i][0][r] * scale;
      float x1 = acc[i][1][r] * scale;
      float c0 = ct[s * NROT + fr],      sn0 = st[s * NROT + fr];
      float c1 = ct[s * NROT + 16 + fr], sn1 = st[s * NROT + 16 + fr];
      float y0 = x0 * c0 - x1 * sn0;
      float y1 = x1 * c1 + x0 * sn1;
      size_t rb = (size_t)gm * NE + n0 + wn * 64;
      Og[rb + 0 * 16 + fr] = (bf16)y0;
      Og[rb + 1 * 16 + fr] = (bf16)y1;
      Og[rb + 2 * 16 + fr] = (bf16)(acc[i][2][r] * scale);
      Og[rb + 3 * 16 + fr] = (bf16)(acc[i][3][r] * scale);
    }
  }
}

// ---- output projection + bias (64x128 tile for 2 blocks/CU) ----
__global__ __launch_bounds__(256) void k_gemm_o(
    const bf16* __restrict__ A, const bf16* __restrict__ W, float* __restrict__ Og,
    const float* __restrict__ bias)
{
  __shared__ bf16 lA[64 * 64];
  __shared__ bf16 lB[128 * 64];
  const int m0 = blockIdx.x * 64, n0 = blockIdx.y * 128;
  f32x4 acc[2][4] = {};
  gemm_core<64, 128>(A, W, lA, lB, m0, n0, acc);

  const int tid = threadIdx.x;
  const int wave = tid >> 6, lane = tid & 63;
  const int wm = wave >> 1, wn = wave & 1;
  const int fr = lane & 15, kg = lane >> 4;
#pragma unroll
  for (int i = 0; i < 2; ++i)
#pragma unroll
    for (int j = 0; j < 4; ++j) {
      int gc = n0 + wn * 64 + j * 16 + fr;
      float bv = bias[gc];
#pragma unroll
      for (int r = 0; r < 4; ++r) {
        int gm = m0 + wm * 32 + i * 16 + kg * 4 + r;
        Og[(size_t)gm * NE + gc] = acc[i][j][r] + bv;
      }
    }
}

// ---- causal flash attention (exp2 domain; q pre-scaled by log2e*D^-0.5) ----
// 128-row q tile / block; 4 waves x 32 q-rows; KV tiles of 64, K double-buffered.
__global__ __launch_bounds__(256) void k_attn(
    const bf16* __restrict__ Q, const bf16* __restrict__ K,
    const bf16* __restrict__ V, bf16* __restrict__ O)
{
  __shared__ bf16 lK[2][64 * 64];
  __shared__ bf16 lVT[64 * 64];
  __shared__ bf16 lP[4][32 * 66];
  const int tid = threadIdx.x;
  const int wave = tid >> 6, lane = tid & 63;
  const int fr = lane & 15, kg = lane >> 4;
  const int bxr = blockIdx.x;                    // 0..7
  const int qi = (bxr < 4) ? bxr : 11 - bxr;     // complement pairing: balance
  const int bh = blockIdx.y;
  const int b = bh >> 4, h = bh & 15;
  const int q0 = qi * 128;
  const int nt = 2 * qi + 2;                     // kv tiles for this q tile
  const size_t hbase = (size_t)b * NS * NE + h * 64;
  const bf16* Qb = Q + hbase;
  const bf16* Kb = K + hbase;
  const bf16* Vb = V + hbase;

  // hoist Q fragments: rows q0 + wave*32 + hl*16 + fr, k = kk*32 + kg*8 + j
  bf16x8 qf[2][2];
#pragma unroll
  for (int hl = 0; hl < 2; ++hl)
#pragma unroll
    for (int kk = 0; kk < 2; ++kk)
      qf[hl][kk] = *reinterpret_cast<const bf16x8*>(
          Qb + (size_t)(q0 + wave * 32 + hl * 16 + fr) * NE + kk * 32 + kg * 8);

  const int vkv = (tid & 31) * 2;
  const int vd0 = (tid >> 5) * 8;
  bf16x8 v0r, v1r;

  auto stageK = [&](int t, int buf) {
    const int kv0 = t * 64;
#pragma unroll
    for (int i = 0; i < 2; ++i) {
      int chunk = i * 4 + wave;
      int row = (chunk << 3) + (lane >> 3);
      int slot = (lane & 7) ^ (row & 7);
      gload_lds16(Kb + (size_t)(kv0 + row) * NE + slot * 8, (char*)lK[buf] + chunk * 1024);
    }
  };
  auto loadV = [&](int t) {
    const int kv0 = t * 64;
    v0r = *reinterpret_cast<const bf16x8*>(Vb + (size_t)(kv0 + vkv) * NE + vd0);
    v1r = *reinterpret_cast<const bf16x8*>(Vb + (size_t)(kv0 + vkv + 1) * NE + vd0);
  };
  auto writeVT = [&]() {
#pragma unroll
    for (int e = 0; e < 8; ++e) {
      int d = vd0 + e;
      int byteoff = d * 128 + (((vkv >> 3) ^ (d & 7)) << 4) + (vkv & 7) * 2;
      bf16x2 pr = { v0r[e], v1r[e] };
      *reinterpret_cast<bf16x2*>((char*)lVT + byteoff) = pr;
    }
  };

  stageK(0, 0);
  loadV(0);
  __syncthreads();     // vmcnt drained: K(0) in lK[0], Vreg(0) in regs
  writeVT();
  __syncthreads();     // VT(0) visible

  f32x4 oacc[2][4] = {};
  float mrow[2][4], lsum[2][4];
#pragma unroll
  for (int hl = 0; hl < 2; ++hl)
#pragma unroll
    for (int r = 0; r < 4; ++r) { mrow[hl][r] = -3.0e38f; lsum[hl][r] = 0.f; }

  for (int t = 0; t < nt; ++t) {
    const int c = t & 1;
    if (t + 1 < nt) { stageK(t + 1, c ^ 1); loadV(t + 1); }   // prefetch under compute

    // QK^T: S[hl][q=kg*4+r][kv=j*16+fr]
    f32x4 sacc[2][4] = {};
    __builtin_amdgcn_s_setprio(1);
#pragma unroll
    for (int kk = 0; kk < 2; ++kk)
#pragma unroll
      for (int j = 0; j < 4; ++j) {
        int rc = j * 16 + fr;
        bf16x8 kf = *reinterpret_cast<const bf16x8*>(
            lK[c] + rc * 64 + (((kg + 4 * kk) ^ (rc & 7)) << 3));
        sacc[0][j] = __builtin_amdgcn_mfma_f32_16x16x32_bf16(qf[0][kk], kf, sacc[0][j], 0, 0, 0);
        sacc[1][j] = __builtin_amdgcn_mfma_f32_16x16x32_bf16(qf[1][kk], kf, sacc[1][j], 0, 0, 0);
      }
    __builtin_amdgcn_s_setprio(0);

    const int kv0 = t * 64;
    if ((t >> 1) == qi) {   // diagonal region: causal mask
#pragma unroll
      for (int hl = 0; hl < 2; ++hl)
#pragma unroll
        for (int j = 0; j < 4; ++j)
#pragma unroll
          for (int r = 0; r < 4; ++r)
            if (kv0 + j * 16 + fr > q0 + wave * 32 + hl * 16 + kg * 4 + r)
              sacc[hl][j][r] = -3.0e38f;
    }

    // online softmax (exp2 domain), DPP rotate-reduce over the row's 16 lanes
#pragma unroll
    for (int hl = 0; hl < 2; ++hl)
#pragma unroll
      for (int r = 0; r < 4; ++r) {
        float tm = fmaxf(fmaxf(sacc[hl][0][r], sacc[hl][1][r]),
                         fmaxf(sacc[hl][2][r], sacc[hl][3][r]));
        tm = fmax_dpp<0x121>(tm); tm = fmax_dpp<0x122>(tm);
        tm = fmax_dpp<0x124>(tm); tm = fmax_dpp<0x128>(tm);
        float nm = fmaxf(mrow[hl][r], tm);
        float corr = exp2f(mrow[hl][r] - nm);
        mrow[hl][r] = nm;
        float ps = 0.f;
#pragma unroll
        for (int j = 0; j < 4; ++j) {
          float p = exp2f(sacc[hl][j][r] - nm);
          ps += p;
          lP[wave][(hl * 16 + kg * 4 + r) * 66 + j * 16 + fr] = (bf16)p;
        }
        ps = fadd_dpp<0x121>(ps); ps = fadd_dpp<0x122>(ps);
        ps = fadd_dpp<0x124>(ps); ps = fadd_dpp<0x128>(ps);
        lsum[hl][r] = lsum[hl][r] * corr + ps;
#pragma unroll
        for (int df = 0; df < 4; ++df) oacc[hl][df][r] *= corr;
      }

    // PV: A = P rows (supply fr), B = V^T (shared vf across halves)
    __builtin_amdgcn_s_setprio(1);
#pragma unroll
    for (int ks = 0; ks < 2; ++ks) {
      bf16x8 pf0 = *reinterpret_cast<const bf16x8*>(&lP[wave][(0 * 16 + fr) * 66 + ks * 32 + kg * 8]);
      bf16x8 pf1 = *reinterpret_cast<const bf16x8*>(&lP[wave][(1 * 16 + fr) * 66 + ks * 32 + kg * 8]);
#pragma unroll
      for (int df = 0; df < 4; ++df) {
        int d = df * 16 + fr;
        bf16x8 vf = *reinterpret_cast<const bf16x8*>(
            (char*)lVT + d * 128 + (((kg + 4 * ks) ^ (d & 7)) << 4));
        oacc[0][df] = __builtin_amdgcn_mfma_f32_16x16x32_bf16(pf0, vf, oacc[0][df], 0, 0, 0);
        oacc[1][df] = __builtin_amdgcn_mfma_f32_16x16x32_bf16(pf1, vf, oacc[1][df], 0, 0, 0);
      }
    }
    __builtin_amdgcn_s_setprio(0);

    __syncthreads();   // everyone done with lK[c] + lVT; vmcnt drained -> K(t+1), Vreg(t+1) ready
    if (t + 1 < nt) { writeVT(); __syncthreads(); }   // VT(t+1) visible
  }

  // epilogue
#pragma unroll
  for (int hl = 0; hl < 2; ++hl)
#pragma unroll
    for (int df = 0; df < 4; ++df)
#pragma unroll
      for (int r = 0; r < 4; ++r) {
        size_t gm = (size_t)b * NS + q0 + wave * 32 + hl * 16 + kg * 4 + r;
        O[gm * NE + h * 64 + df * 16 + fr] = (bf16)(oacc[hl][df][r] / lsum[hl][r]);
      }
}

extern "C" void kernel_launch(void* const* d_in, const int* in_sizes, int n_in,
                              void* d_out, int out_size, void* d_ws, size_t ws_size,
                              hipStream_t stream) {
  const float* hs  = (const float*)d_in[0];
  const float* rot = (const float*)d_in[1];
  const float* qw  = (const float*)d_in[2];
  const float* kw  = (const float*)d_in[3];
  const float* vw  = (const float*)d_in[4];
  const float* ow  = (const float*)d_in[5];
  const float* obb = (const float*)d_in[6];
  float* out = (float*)d_out;

  char* ws = (char*)d_ws;
  size_t off = 0;
  bf16* hb  = (bf16*)(ws + off); off += (size_t)NM * NE * 2;
  bf16* wqb = (bf16*)(ws + off); off += (size_t)NE * NE * 2;
  bf16* wkb = (bf16*)(ws + off); off += (size_t)NE * NE * 2;
  bf16* wvb = (bf16*)(ws + off); off += (size_t)NE * NE * 2;
  bf16* wob = (bf16*)(ws + off); off += (size_t)NE * NE * 2;
  bf16* qb  = (bf16*)(ws + off); off += (size_t)NM * NE * 2;
  bf16* kb  = (bf16*)(ws + off); off += (size_t)NM * NE * 2;
  bf16* vb  = (bf16*)(ws + off); off += (size_t)NM * NE * 2;
  float* ct = (float*)(ws + off); off += (size_t)NS * NROT * 4;
  float* st = (float*)(ws + off); off += (size_t)NS * NROT * 4;
  bf16* aob = hb;   // hidden bf16 is dead after QKV GEMMs

  // prep: hidden cvt, 4x weight cvt (one launch), rope tables
  k_cvt<<<dim3((NM * NE / 4 + 255) / 256), dim3(256), 0, stream>>>(hs, hb, NM * NE / 4);
  Cvt4Args ca = { qw, kw, vw, ow, wqb, wkb, wvb, wob };
  k_cvt4<<<dim3(NE * NE / 4 / 256, 4), dim3(256), 0, stream>>>(ca, NE * NE / 4);
  k_tab<<<dim3((NS * NROT + 255) / 256), dim3(256), 0, stream>>>(rot, ct, st, NS * NROT);

  // fused QKV projections + rope (one dispatch, 768 blocks)
  k_gemm_qkv<<<dim3(NM / 128, NE / 128, 3), dim3(256), 0, stream>>>(
      hb, wqb, wkb, wvb, qb, kb, vb, ct, st);

  // causal flash attention
  k_attn<<<dim3(NS / 128, NB * NH), dim3(256), 0, stream>>>(qb, kb, vb, aob);

  // output projection + bias
  k_gemm_o<<<dim3(NM / 64, NE / 128), dim3(256), 0, stream>>>(aob, wob, out, obb);

  (void)in_sizes; (void)n_in; (void)out_size; (void)ws_size;
}